// Round 6
// baseline (9897.105 us; speedup 1.0000x reference)
//
#include <hip/hip_runtime.h>

#define HIDDEN 15
#define XDIM 8192
#define XOUT 8191
#define NL 5

#define REP15(F) F(0) F(1) F(2) F(3) F(4) F(5) F(6) F(7) F(8) F(9) F(10) F(11) F(12) F(13) F(14)

// IR-level optimization barrier: may-write-all-memory => GVN/LICM cannot hoist
// LDS weight loads across it. Emits no instructions. This is the fix for the
// r3/r5 meltdown (all 1205 weight floats hoisted live -> 8KB/thread scratch).
#define FENCE asm volatile("" ::: "memory");

// 15-weight dot + bias, weights in 4 float4s (bias = q3.w), activations = named scalars P_0..P_14
#define DOTL(q0, q1, q2, q3, P)                                  \
    fmaf((q0).x, P##_0,                                          \
    fmaf((q0).y, P##_1,                                          \
    fmaf((q0).z, P##_2,                                          \
    fmaf((q0).w, P##_3,                                          \
    fmaf((q1).x, P##_4,                                          \
    fmaf((q1).y, P##_5,                                          \
    fmaf((q1).z, P##_6,                                          \
    fmaf((q1).w, P##_7,                                          \
    fmaf((q2).x, P##_8,                                          \
    fmaf((q2).y, P##_9,                                          \
    fmaf((q2).z, P##_10,                                         \
    fmaf((q2).w, P##_11,                                         \
    fmaf((q3).x, P##_12,                                         \
    fmaf((q3).y, P##_13,                                         \
    fmaf((q3).z, P##_14, (q3).w)))))))))))))))

__global__ __attribute__((amdgpu_flat_work_group_size(256, 256), amdgpu_waves_per_eu(4)))
void cnn_stencil_kernel(
    const float* __restrict__ rho,
    const float* __restrict__ w0,
    const float* __restrict__ b0,
    const float* __restrict__ Wh,
    const float* __restrict__ bh,
    const float* __restrict__ Wl,
    const float* __restrict__ bl,
    float* __restrict__ out) {
    __shared__ float sFC[HIDDEN][4];        // {w0[2c], w0[2c+1], b0[c], 0}
    __shared__ float sWh[NL][HIDDEN][16];   // [l][o][0..14]=Wh row, [15]=bh
    __shared__ float sWl[16];               // [0..14]=Wl, [15]=bl

    const int tid = threadIdx.x;

    // ---- stage weights into LDS (packed rows, bias in slot 15) ----
    for (int i = tid; i < NL * HIDDEN * 16; i += 256) {
        const int w = i >> 4;   // l*15 + o
        const int k = i & 15;
        (&sWh[0][0][0])[i] = (k < 15) ? Wh[w * 15 + k] : bh[w];
    }
    if (tid < HIDDEN * 4) {
        const int c = tid >> 2;
        const int k = tid & 3;
        sFC[c][k] = (k == 0) ? w0[2 * c] : (k == 1) ? w0[2 * c + 1] : (k == 2) ? b0[c] : 0.0f;
    }
    if (tid < 16) sWl[tid] = (tid < 15) ? Wl[tid] : bl[0];
    __syncthreads();

    const int b = blockIdx.x >> 4;             // 16 blocks per row
    const int chunk = blockIdx.x & 15;
    const int x0 = chunk * 512 + tid;          // [0, 7935]
    const int x1 = x0 + 256;                   // [256, 8191]
    const float* rrow = rho + (size_t)b * XDIM;
    float* orow = out + (size_t)b * XOUT;

    const float r00 = rrow[x0];
    const float r01 = rrow[x0 + 1];            // <= 7936, in bounds
    const float r10 = rrow[x1];
    const int x1n = (x1 + 1 <= XDIM - 1) ? (x1 + 1) : (XDIM - 1);
    const float r11 = rrow[x1n];

    // named scalar activations (never indexable, address never taken -> SSA -> VGPRs)
#define DECLV(o) float a0_##o, a1_##o, t0_##o, t1_##o;
    REP15(DECLV)
#undef DECLV

    // ---- first conv (k=2) + relu ----
#define FCONV(c)                                                         \
    {                                                                    \
        const float4 q = *(const float4*)&sFC[c][0];                     \
        a0_##c = fmaxf(fmaf(q.x, r00, fmaf(q.y, r01, q.z)), 0.0f);       \
        a1_##c = fmaxf(fmaf(q.x, r10, fmaf(q.y, r11, q.z)), 0.0f);       \
    }
    REP15(FCONV)
#undef FCONV
    FENCE

    // ---- hidden 15x15 layers: LDS-broadcast weight row feeds both positions ----
#define ROW(l, o, SA, SB, DA, DB)                                        \
    {                                                                    \
        const float4 q0 = *(const float4*)&sWh[l][o][0];                 \
        const float4 q1 = *(const float4*)&sWh[l][o][4];                 \
        const float4 q2 = *(const float4*)&sWh[l][o][8];                 \
        const float4 q3 = *(const float4*)&sWh[l][o][12];                \
        DA##_##o = fmaxf(DOTL(q0, q1, q2, q3, SA), 0.0f);                \
        DB##_##o = fmaxf(DOTL(q0, q1, q2, q3, SB), 0.0f);                \
    }
// 2 rows per fenced region: <= 32 weight floats live at once (+~60 activations)
#define LAYER(l, SA, SB, DA, DB)                                         \
    ROW(l, 0, SA, SB, DA, DB)  ROW(l, 1, SA, SB, DA, DB)  FENCE          \
    ROW(l, 2, SA, SB, DA, DB)  ROW(l, 3, SA, SB, DA, DB)  FENCE          \
    ROW(l, 4, SA, SB, DA, DB)  ROW(l, 5, SA, SB, DA, DB)  FENCE          \
    ROW(l, 6, SA, SB, DA, DB)  ROW(l, 7, SA, SB, DA, DB)  FENCE          \
    ROW(l, 8, SA, SB, DA, DB)  ROW(l, 9, SA, SB, DA, DB)  FENCE          \
    ROW(l, 10, SA, SB, DA, DB) ROW(l, 11, SA, SB, DA, DB) FENCE          \
    ROW(l, 12, SA, SB, DA, DB) ROW(l, 13, SA, SB, DA, DB) FENCE          \
    ROW(l, 14, SA, SB, DA, DB)                            FENCE

    LAYER(0, a0, a1, t0, t1)
    LAYER(1, t0, t1, a0, a1)
    LAYER(2, a0, a1, t0, t1)
    LAYER(3, t0, t1, a0, a1)
    LAYER(4, a0, a1, t0, t1)   // result in t0_*/t1_*
#undef LAYER
#undef ROW

    // ---- final dot (bias = f3.w) + clip ----
    const float4 f0 = *(const float4*)&sWl[0];
    const float4 f1 = *(const float4*)&sWl[4];
    const float4 f2 = *(const float4*)&sWl[8];
    const float4 f3 = *(const float4*)&sWl[12];
    float y0 = DOTL(f0, f1, f2, f3, t0);
    float y1 = DOTL(f0, f1, f2, f3, t1);
    y0 = fminf(fmaxf(y0, 0.0f), 1.0f);
    y1 = fminf(fmaxf(y1, 0.0f), 1.0f);

    orow[x0] = y0;                  // x0 <= 7935 < 8191, always valid
    if (x1 < XOUT) orow[x1] = y1;   // mask single x==8191 slot
}

extern "C" void kernel_launch(void* const* d_in, const int* in_sizes, int n_in,
                              void* d_out, int out_size, void* d_ws, size_t ws_size,
                              hipStream_t stream) {
    const float* rho = (const float*)d_in[0];
    const float* w0  = (const float*)d_in[1];
    const float* b0  = (const float*)d_in[2];
    const float* Wh  = (const float*)d_in[3];
    const float* bh  = (const float*)d_in[4];
    const float* Wl  = (const float*)d_in[5];
    const float* bl  = (const float*)d_in[6];
    float* out = (float*)d_out;

    const int nrows = 1024;
    dim3 grid(nrows * 16);   // 16 blocks x 256 threads x 2 positions = 8192 slots/row
    dim3 block(256);
    cnn_stencil_kernel<<<grid, block, 0, stream>>>(rho, w0, b0, Wh, bh, Wl, bl, out);
}

// Round 7
// 582.091 us; speedup vs baseline: 17.0027x; 17.0027x over previous
//
#include <hip/hip_runtime.h>

#define XDIM 8192
#define XOUT 8191

#define REP15(F) F(0) F(1) F(2) F(3) F(4) F(5) F(6) F(7) F(8) F(9) F(10) F(11) F(12) F(13) F(14)

// IR-level optimization barrier: may-write-all-memory, so GVN/LICM cannot
// hoist (or CSE) the uniform weight loads across it. Emits no instructions.
// Bounds live weight SGPRs to one region's worth (~48+20 < 102 cap).
#define FENCE asm volatile("" ::: "memory");

// 15-term dot + bias for hidden layer l, output row o, over named scalars P_0..P_14.
// Weight refs are wave-uniform with compile-time offsets -> s_load -> SGPR operand of v_fmac.
#define DOTH(l, o, P)                                            \
    fmaf(Wh[(l)*225+(o)*15+0],  P##_0,                           \
    fmaf(Wh[(l)*225+(o)*15+1],  P##_1,                           \
    fmaf(Wh[(l)*225+(o)*15+2],  P##_2,                           \
    fmaf(Wh[(l)*225+(o)*15+3],  P##_3,                           \
    fmaf(Wh[(l)*225+(o)*15+4],  P##_4,                           \
    fmaf(Wh[(l)*225+(o)*15+5],  P##_5,                           \
    fmaf(Wh[(l)*225+(o)*15+6],  P##_6,                           \
    fmaf(Wh[(l)*225+(o)*15+7],  P##_7,                           \
    fmaf(Wh[(l)*225+(o)*15+8],  P##_8,                           \
    fmaf(Wh[(l)*225+(o)*15+9],  P##_9,                           \
    fmaf(Wh[(l)*225+(o)*15+10], P##_10,                          \
    fmaf(Wh[(l)*225+(o)*15+11], P##_11,                          \
    fmaf(Wh[(l)*225+(o)*15+12], P##_12,                          \
    fmaf(Wh[(l)*225+(o)*15+13], P##_13,                          \
    fmaf(Wh[(l)*225+(o)*15+14], P##_14, bh[(l)*15+(o)])))))))))))))))

// final 15-term dot + bias
#define DOTF(P)                                                  \
    fmaf(Wl[0],  P##_0,                                          \
    fmaf(Wl[1],  P##_1,                                          \
    fmaf(Wl[2],  P##_2,                                          \
    fmaf(Wl[3],  P##_3,                                          \
    fmaf(Wl[4],  P##_4,                                          \
    fmaf(Wl[5],  P##_5,                                          \
    fmaf(Wl[6],  P##_6,                                          \
    fmaf(Wl[7],  P##_7,                                          \
    fmaf(Wl[8],  P##_8,                                          \
    fmaf(Wl[9],  P##_9,                                          \
    fmaf(Wl[10], P##_10,                                         \
    fmaf(Wl[11], P##_11,                                         \
    fmaf(Wl[12], P##_12,                                         \
    fmaf(Wl[13], P##_13,                                         \
    fmaf(Wl[14], P##_14, bl[0])))))))))))))))

// one output row: both positions reuse the same SGPR weight row
#define ROW(l, o, S, D)                                          \
    D##0_##o = fmaxf(DOTH(l, o, S##0), 0.0f);                    \
    D##1_##o = fmaxf(DOTH(l, o, S##1), 0.0f);

// 15x15 layer: 3 rows (48 weight floats) per fenced region
#define LAYER(l, S, D)                                           \
    ROW(l, 0, S, D)  ROW(l, 1, S, D)  ROW(l, 2, S, D)  FENCE     \
    ROW(l, 3, S, D)  ROW(l, 4, S, D)  ROW(l, 5, S, D)  FENCE     \
    ROW(l, 6, S, D)  ROW(l, 7, S, D)  ROW(l, 8, S, D)  FENCE     \
    ROW(l, 9, S, D)  ROW(l, 10, S, D) ROW(l, 11, S, D) FENCE     \
    ROW(l, 12, S, D) ROW(l, 13, S, D) ROW(l, 14, S, D) FENCE

__global__ __attribute__((amdgpu_flat_work_group_size(256, 256), amdgpu_waves_per_eu(4, 4)))
void cnn_stencil_kernel(
    const float* __restrict__ rho,
    const float* __restrict__ w0,
    const float* __restrict__ b0,
    const float* __restrict__ Wh,
    const float* __restrict__ bh,
    const float* __restrict__ Wl,
    const float* __restrict__ bl,
    float* __restrict__ out) {
    const int tid = threadIdx.x;
    const int b = blockIdx.x >> 4;             // 16 blocks per row
    const int chunk = blockIdx.x & 15;
    const int x0 = chunk * 512 + tid;          // [0, 7935]
    const int x1 = x0 + 256;                   // [256, 8191]
    const float* rrow = rho + (size_t)b * XDIM;
    float* orow = out + (size_t)b * XOUT;

    const float r00 = rrow[x0];
    const float r01 = rrow[x0 + 1];            // <= 7936, in bounds
    const float r10 = rrow[x1];
    const int x1n = (x1 + 1 <= XDIM - 1) ? (x1 + 1) : (XDIM - 1);
    const float r11 = rrow[x1n];

    // named scalar activations: never indexable, address never taken -> SSA -> VGPRs
#define DECLV(o) float a0_##o, a1_##o, t0_##o, t1_##o;
    REP15(DECLV)
#undef DECLV

    // ---- first conv (k=2) + relu, fenced in halves (45 uniform scalars total) ----
#define FC(c)                                                                    \
    a0_##c = fmaxf(fmaf(w0[2*(c)], r00, fmaf(w0[2*(c)+1], r01, b0[(c)])), 0.0f); \
    a1_##c = fmaxf(fmaf(w0[2*(c)], r10, fmaf(w0[2*(c)+1], r11, b0[(c)])), 0.0f);
    FC(0) FC(1) FC(2) FC(3) FC(4) FC(5) FC(6) FC(7)
    FENCE
    FC(8) FC(9) FC(10) FC(11) FC(12) FC(13) FC(14)
    FENCE
#undef FC

    // ---- 5 hidden 15x15 layers, ping-pong a <-> t ----
    LAYER(0, a, t)
    LAYER(1, t, a)
    LAYER(2, a, t)
    LAYER(3, t, a)
    LAYER(4, a, t)   // result in t0_* / t1_*

    // ---- final dot + clip ----
    float y0 = DOTF(t0);
    float y1 = DOTF(t1);
    y0 = fminf(fmaxf(y0, 0.0f), 1.0f);
    y1 = fminf(fmaxf(y1, 0.0f), 1.0f);

    orow[x0] = y0;                  // x0 <= 7935 < 8191, always valid
    if (x1 < XOUT) orow[x1] = y1;   // mask the single x==8191 slot
}

extern "C" void kernel_launch(void* const* d_in, const int* in_sizes, int n_in,
                              void* d_out, int out_size, void* d_ws, size_t ws_size,
                              hipStream_t stream) {
    const float* rho = (const float*)d_in[0];
    const float* w0  = (const float*)d_in[1];
    const float* b0  = (const float*)d_in[2];
    const float* Wh  = (const float*)d_in[3];
    const float* bh  = (const float*)d_in[4];
    const float* Wl  = (const float*)d_in[5];
    const float* bl  = (const float*)d_in[6];
    float* out = (float*)d_out;

    const int nrows = 1024;
    dim3 grid(nrows * 16);   // 16 blocks x 256 threads x 2 positions = 8192 slots/row
    dim3 block(256);
    cnn_stencil_kernel<<<grid, block, 0, stream>>>(rho, w0, b0, Wh, bh, Wl, bl, out);
}

// Round 9
// 161.533 us; speedup vs baseline: 61.2699x; 3.6035x over previous
//
#include <hip/hip_runtime.h>

typedef __attribute__((ext_vector_type(4))) _Float16 half4;
typedef __attribute__((ext_vector_type(4))) float f32x4;

#define XDIM 8192
#define XOUT 8191
#define TPW 16                     // tiles (of 16 positions) per wave
#define NTILES (1024 * 512)        // 512 tiles per row, 1024 rows
#define NBLOCKS (NTILES / TPW / 4) // 4 waves per block

// Split 4 f32 into hi/lo half4 fragments via scalar casts (RTN). The residual
// e = h - (float)hi is exact in fp32, so hi+lo carries ~22 mantissa bits.
#define SPLIT4(H0, H1, H2, H3, BH, BL)                                      \
    {                                                                       \
        (BH).x = (_Float16)(H0);                                            \
        (BH).y = (_Float16)(H1);                                            \
        (BH).z = (_Float16)(H2);                                            \
        (BH).w = (_Float16)(H3);                                            \
        (BL).x = (_Float16)((H0) - (float)(BH).x);                          \
        (BL).y = (_Float16)((H1) - (float)(BH).y);                          \
        (BL).z = (_Float16)((H2) - (float)(BH).z);                          \
        (BL).w = (_Float16)((H3) - (float)(BH).w);                          \
    }

#define MFMA16(A, B, C) __builtin_amdgcn_mfma_f32_16x16x16f16((A), (B), (C), 0, 0, 0)

__global__ __launch_bounds__(256) void cnn_mfma_kernel(
    const float* __restrict__ rho, const float* __restrict__ w0,
    const float* __restrict__ b0, const float* __restrict__ Wh,
    const float* __restrict__ bh, const float* __restrict__ Wl,
    const float* __restrict__ bl, float* __restrict__ out) {
    const int lane = threadIdx.x & 63;
    const int lm = lane & 15;          // A-row (out ch) / B-col (position) / D-col
    const int kb = (lane >> 4) * 4;    // A/B k-base, D row-base (4 regs)

    // ---- per-lane weight fragments, loaded once (vector path, ~30 VGPRs;
    //      no uniform loads -> no SGPR pressure, nothing for GVN to hoist) ----
    half4 Ah0, Al0, Ah1, Al1, Ah2, Al2, Ah3, Al3, Ah4, Al4;
#define LOADA(L, AH, AL)                                                          \
    {                                                                             \
        float _w0 = (lm < 15 && kb + 0 < 15) ? Wh[(L)*225 + lm*15 + kb + 0] : 0.f;\
        float _w1 = (lm < 15 && kb + 1 < 15) ? Wh[(L)*225 + lm*15 + kb + 1] : 0.f;\
        float _w2 = (lm < 15 && kb + 2 < 15) ? Wh[(L)*225 + lm*15 + kb + 2] : 0.f;\
        float _w3 = (lm < 15 && kb + 3 < 15) ? Wh[(L)*225 + lm*15 + kb + 3] : 0.f;\
        SPLIT4(_w0, _w1, _w2, _w3, AH, AL)                                        \
    }
    LOADA(0, Ah0, Al0)
    LOADA(1, Ah1, Al1)
    LOADA(2, Ah2, Al2)
    LOADA(3, Ah3, Al3)
    LOADA(4, Ah4, Al4)
#undef LOADA

    f32x4 bias0, bias1, bias2, bias3, bias4;   // C-init per layer (rows kb..kb+3)
#define LOADB(L, BV)                                                  \
    {                                                                 \
        (BV).x = (kb + 0 < 15) ? bh[(L)*15 + kb + 0] : 0.f;           \
        (BV).y = (kb + 1 < 15) ? bh[(L)*15 + kb + 1] : 0.f;           \
        (BV).z = (kb + 2 < 15) ? bh[(L)*15 + kb + 2] : 0.f;           \
        (BV).w = (kb + 3 < 15) ? bh[(L)*15 + kb + 3] : 0.f;           \
    }
    LOADB(0, bias0)
    LOADB(1, bias1)
    LOADB(2, bias2)
    LOADB(3, bias3)
    LOADB(4, bias4)
#undef LOADB

    // first-conv weights for this lane's 4 channels (kb..kb+3); ch 15 -> 0
    const float fw0_0 = (kb + 0 < 15) ? w0[2*(kb+0)]   : 0.f;
    const float fw1_0 = (kb + 0 < 15) ? w0[2*(kb+0)+1] : 0.f;
    const float fb_0  = (kb + 0 < 15) ? b0[kb+0]       : 0.f;
    const float fw0_1 = (kb + 1 < 15) ? w0[2*(kb+1)]   : 0.f;
    const float fw1_1 = (kb + 1 < 15) ? w0[2*(kb+1)+1] : 0.f;
    const float fb_1  = (kb + 1 < 15) ? b0[kb+1]       : 0.f;
    const float fw0_2 = (kb + 2 < 15) ? w0[2*(kb+2)]   : 0.f;
    const float fw1_2 = (kb + 2 < 15) ? w0[2*(kb+2)+1] : 0.f;
    const float fb_2  = (kb + 2 < 15) ? b0[kb+2]       : 0.f;
    const float fw0_3 = (kb + 3 < 15) ? w0[2*(kb+3)]   : 0.f;
    const float fw1_3 = (kb + 3 < 15) ? w0[2*(kb+3)+1] : 0.f;
    const float fb_3  = (kb + 3 < 15) ? b0[kb+3]       : 0.f;

    const float wl0 = (kb + 0 < 15) ? Wl[kb + 0] : 0.f;
    const float wl1 = (kb + 1 < 15) ? Wl[kb + 1] : 0.f;
    const float wl2 = (kb + 2 < 15) ? Wl[kb + 2] : 0.f;
    const float wl3 = (kb + 3 < 15) ? Wl[kb + 3] : 0.f;
    const float bl0 = bl[0];

    const int wib = threadIdx.x >> 6;
    const int tbase = (blockIdx.x * 4 + wib) * TPW;

#pragma unroll 2
    for (int t = 0; t < TPW; ++t) {
        const int tile = tbase + t;
        const int brow = tile >> 9;            // 512 tiles per row
        const int x = ((tile & 511) << 4) + lm;   // <= 8191
        const float* rrow = rho + (size_t)brow * XDIM;
        const float r0 = rrow[x];
        const float r1 = rrow[(x < XDIM - 1) ? x + 1 : XDIM - 1];

        // first conv (k=2) + relu, this lane's 4 channels of its position
        float h0 = fmaxf(fmaf(fw0_0, r0, fmaf(fw1_0, r1, fb_0)), 0.f);
        float h1 = fmaxf(fmaf(fw0_1, r0, fmaf(fw1_1, r1, fb_1)), 0.f);
        float h2 = fmaxf(fmaf(fw0_2, r0, fmaf(fw1_2, r1, fb_2)), 0.f);
        float h3 = fmaxf(fmaf(fw0_3, r0, fmaf(fw1_3, r1, fb_3)), 0.f);

        half4 bhi, blo;
        SPLIT4(h0, h1, h2, h3, bhi, blo)

        // hidden layer: bias + Whi*hhi + Whi*hlo + Wlo*hhi, relu.
        // D fragment maps (col=lane&15,row=kb+reg) == next B (col,k) -> no shuffles.
#define HLAYER(AH, AL, BV)                                   \
        {                                                    \
            f32x4 _acc = (BV);                               \
            _acc = MFMA16((AH), bhi, _acc);                  \
            _acc = MFMA16((AH), blo, _acc);                  \
            _acc = MFMA16((AL), bhi, _acc);                  \
            h0 = fmaxf(_acc.x, 0.f);                         \
            h1 = fmaxf(_acc.y, 0.f);                         \
            h2 = fmaxf(_acc.z, 0.f);                         \
            h3 = fmaxf(_acc.w, 0.f);                         \
        }
        HLAYER(Ah0, Al0, bias0)
        SPLIT4(h0, h1, h2, h3, bhi, blo)
        HLAYER(Ah1, Al1, bias1)
        SPLIT4(h0, h1, h2, h3, bhi, blo)
        HLAYER(Ah2, Al2, bias2)
        SPLIT4(h0, h1, h2, h3, bhi, blo)
        HLAYER(Ah3, Al3, bias3)
        SPLIT4(h0, h1, h2, h3, bhi, blo)
        HLAYER(Ah4, Al4, bias4)
#undef HLAYER

        // final dot: partial over this lane's 4 rows (f32, no conversion),
        // then butterfly-sum the 4 lane groups; clip; lanes 0-15 store.
        float s = fmaf(wl0, h0, fmaf(wl1, h1, fmaf(wl2, h2, wl3 * h3)));
        s += __shfl_xor(s, 16, 64);
        s += __shfl_xor(s, 32, 64);
        const float y = fminf(fmaxf(s + bl0, 0.f), 1.f);
        if (lane < 16 && x < XOUT) out[(size_t)brow * XOUT + x] = y;
    }
}

extern "C" void kernel_launch(void* const* d_in, const int* in_sizes, int n_in,
                              void* d_out, int out_size, void* d_ws, size_t ws_size,
                              hipStream_t stream) {
    const float* rho = (const float*)d_in[0];
    const float* w0  = (const float*)d_in[1];
    const float* b0  = (const float*)d_in[2];
    const float* Wh  = (const float*)d_in[3];
    const float* bh  = (const float*)d_in[4];
    const float* Wl  = (const float*)d_in[5];
    const float* bl  = (const float*)d_in[6];
    float* out = (float*)d_out;

    dim3 grid(NBLOCKS);   // 8192 blocks x 4 waves x 16 tiles x 16 pos = 8.39M
    dim3 block(256);
    cnn_mfma_kernel<<<grid, block, 0, stream>>>(rho, w0, b0, Wh, bh, Wl, bl, out);
}

// Round 10
// 142.530 us; speedup vs baseline: 69.4386x; 1.1333x over previous
//
#include <hip/hip_runtime.h>

typedef __attribute__((ext_vector_type(4))) _Float16 half4;
typedef __attribute__((ext_vector_type(2))) __fp16 fp16x2;
typedef __attribute__((ext_vector_type(4))) float f32x4;

#define XDIM 8192
#define XOUT 8191
#define TPW 16                     // tiles (of 16 positions) per wave
#define NTILES (1024 * 512)        // 512 tiles per row, 1024 rows
#define NBLOCKS (NTILES / TPW / 4) // 4 waves per block

union H4 {
    fp16x2 p[2];
    half4 v;
};

// Split 4 f32 into hi/lo half4 fragments. v_cvt_pkrtz_f16_f32 packs 2 values
// in ONE instruction; residual e = h - (float)hi is exact in f32 (RTZ => |e| <
// ulp), written as fmaf(-1, ext(hi), h) to match v_fma_mix_f32 selection.
#define SPLIT4(H0, H1, H2, H3, BH, BL)                                      \
    {                                                                       \
        H4 _uh, _ul;                                                        \
        _uh.p[0] = __builtin_amdgcn_cvt_pkrtz((H0), (H1));                  \
        _uh.p[1] = __builtin_amdgcn_cvt_pkrtz((H2), (H3));                  \
        const float _e0 = fmaf(-1.0f, (float)_uh.p[0].x, (H0));             \
        const float _e1 = fmaf(-1.0f, (float)_uh.p[0].y, (H1));             \
        const float _e2 = fmaf(-1.0f, (float)_uh.p[1].x, (H2));             \
        const float _e3 = fmaf(-1.0f, (float)_uh.p[1].y, (H3));             \
        _ul.p[0] = __builtin_amdgcn_cvt_pkrtz(_e0, _e1);                    \
        _ul.p[1] = __builtin_amdgcn_cvt_pkrtz(_e2, _e3);                    \
        (BH) = _uh.v;                                                       \
        (BL) = _ul.v;                                                       \
    }

#define MFMA16(A, B, C) __builtin_amdgcn_mfma_f32_16x16x16f16((A), (B), (C), 0, 0, 0)

__global__ __launch_bounds__(256) void cnn_mfma_kernel(
    const float* __restrict__ rho, const float* __restrict__ w0,
    const float* __restrict__ b0, const float* __restrict__ Wh,
    const float* __restrict__ bh, const float* __restrict__ Wl,
    const float* __restrict__ bl, float* __restrict__ out) {
    const int lane = threadIdx.x & 63;
    const int lm = lane & 15;          // A-row (out ch) / B-col (position) / D-col
    const int kb = (lane >> 4) * 4;    // A/B k-base, D row-base (4 regs)

    // ---- per-lane weight fragments, loaded once (no uniform loads -> no
    //      SGPR pressure, nothing for GVN to hoist; verified layout from r9) ----
    half4 Ah0, Al0, Ah1, Al1, Ah2, Al2, Ah3, Al3, Ah4, Al4;
#define LOADA(L, AH, AL)                                                          \
    {                                                                             \
        float _w0 = (lm < 15 && kb + 0 < 15) ? Wh[(L)*225 + lm*15 + kb + 0] : 0.f;\
        float _w1 = (lm < 15 && kb + 1 < 15) ? Wh[(L)*225 + lm*15 + kb + 1] : 0.f;\
        float _w2 = (lm < 15 && kb + 2 < 15) ? Wh[(L)*225 + lm*15 + kb + 2] : 0.f;\
        float _w3 = (lm < 15 && kb + 3 < 15) ? Wh[(L)*225 + lm*15 + kb + 3] : 0.f;\
        SPLIT4(_w0, _w1, _w2, _w3, AH, AL)                                        \
    }
    LOADA(0, Ah0, Al0)
    LOADA(1, Ah1, Al1)
    LOADA(2, Ah2, Al2)
    LOADA(3, Ah3, Al3)
    LOADA(4, Ah4, Al4)
#undef LOADA

    f32x4 bias0, bias1, bias2, bias3, bias4;   // C-init per layer (rows kb..kb+3)
#define LOADB(L, BV)                                                  \
    {                                                                 \
        (BV).x = (kb + 0 < 15) ? bh[(L)*15 + kb + 0] : 0.f;           \
        (BV).y = (kb + 1 < 15) ? bh[(L)*15 + kb + 1] : 0.f;           \
        (BV).z = (kb + 2 < 15) ? bh[(L)*15 + kb + 2] : 0.f;           \
        (BV).w = (kb + 3 < 15) ? bh[(L)*15 + kb + 3] : 0.f;           \
    }
    LOADB(0, bias0)
    LOADB(1, bias1)
    LOADB(2, bias2)
    LOADB(3, bias3)
    LOADB(4, bias4)
#undef LOADB

    // first-conv weights for this lane's 4 channels (kb..kb+3); ch 15 -> 0
    const float fw0_0 = (kb + 0 < 15) ? w0[2*(kb+0)]   : 0.f;
    const float fw1_0 = (kb + 0 < 15) ? w0[2*(kb+0)+1] : 0.f;
    const float fb_0  = (kb + 0 < 15) ? b0[kb+0]       : 0.f;
    const float fw0_1 = (kb + 1 < 15) ? w0[2*(kb+1)]   : 0.f;
    const float fw1_1 = (kb + 1 < 15) ? w0[2*(kb+1)+1] : 0.f;
    const float fb_1  = (kb + 1 < 15) ? b0[kb+1]       : 0.f;
    const float fw0_2 = (kb + 2 < 15) ? w0[2*(kb+2)]   : 0.f;
    const float fw1_2 = (kb + 2 < 15) ? w0[2*(kb+2)+1] : 0.f;
    const float fb_2  = (kb + 2 < 15) ? b0[kb+2]       : 0.f;
    const float fw0_3 = (kb + 3 < 15) ? w0[2*(kb+3)]   : 0.f;
    const float fw1_3 = (kb + 3 < 15) ? w0[2*(kb+3)+1] : 0.f;
    const float fb_3  = (kb + 3 < 15) ? b0[kb+3]       : 0.f;

    const float wl0 = (kb + 0 < 15) ? Wl[kb + 0] : 0.f;
    const float wl1 = (kb + 1 < 15) ? Wl[kb + 1] : 0.f;
    const float wl2 = (kb + 2 < 15) ? Wl[kb + 2] : 0.f;
    const float wl3 = (kb + 3 < 15) ? Wl[kb + 3] : 0.f;
    const float bl0 = bl[0];

    // ---- strength-reduced tiling: each wave owns 16 consecutive tiles of one
    //      row (32 waves cover a row of 512 tiles) -> row ptr hoisted ----
    const int wid = blockIdx.x * 4 + (threadIdx.x >> 6);   // 0..32767
    const int brow = wid >> 5;                             // 32 waves per row
    const int xb = ((wid & 31) << 8) + lm;                 // + t*16, t in [0,16)
    const float* rrow = rho + (size_t)brow * XDIM;
    float* orow = out + (size_t)brow * XOUT;

#pragma unroll 2
    for (int t = 0; t < TPW; ++t) {
        const int x = xb + t * 16;                 // <= 8191
        const float r0 = rrow[x];
        const float r1 = rrow[(x < XDIM - 1) ? x + 1 : XDIM - 1];

        // first conv (k=2) + relu, this lane's 4 channels of its position
        float h0 = fmaxf(fmaf(fw0_0, r0, fmaf(fw1_0, r1, fb_0)), 0.f);
        float h1 = fmaxf(fmaf(fw0_1, r0, fmaf(fw1_1, r1, fb_1)), 0.f);
        float h2 = fmaxf(fmaf(fw0_2, r0, fmaf(fw1_2, r1, fb_2)), 0.f);
        float h3 = fmaxf(fmaf(fw0_3, r0, fmaf(fw1_3, r1, fb_3)), 0.f);

        half4 bhi, blo;
        SPLIT4(h0, h1, h2, h3, bhi, blo)

        // hidden layer: bias + Whi*hhi + Whi*hlo + Wlo*hhi, relu.
        // D fragment maps (col=lane&15,row=kb+reg) == next B (col,k) -> no shuffles.
#define HLAYER(AH, AL, BV)                                   \
        {                                                    \
            f32x4 _acc = (BV);                               \
            _acc = MFMA16((AH), bhi, _acc);                  \
            _acc = MFMA16((AH), blo, _acc);                  \
            _acc = MFMA16((AL), bhi, _acc);                  \
            h0 = fmaxf(_acc.x, 0.f);                         \
            h1 = fmaxf(_acc.y, 0.f);                         \
            h2 = fmaxf(_acc.z, 0.f);                         \
            h3 = fmaxf(_acc.w, 0.f);                         \
        }
        HLAYER(Ah0, Al0, bias0)
        SPLIT4(h0, h1, h2, h3, bhi, blo)
        HLAYER(Ah1, Al1, bias1)
        SPLIT4(h0, h1, h2, h3, bhi, blo)
        HLAYER(Ah2, Al2, bias2)
        SPLIT4(h0, h1, h2, h3, bhi, blo)
        HLAYER(Ah3, Al3, bias3)
        SPLIT4(h0, h1, h2, h3, bhi, blo)
        HLAYER(Ah4, Al4, bias4)
#undef HLAYER

        // final dot: partial over this lane's 4 rows (f32), butterfly-sum the
        // 4 lane groups, clip; lanes 0-15 store.
        float s = fmaf(wl0, h0, fmaf(wl1, h1, fmaf(wl2, h2, wl3 * h3)));
        s += __shfl_xor(s, 16, 64);
        s += __shfl_xor(s, 32, 64);
        const float y = fminf(fmaxf(s + bl0, 0.f), 1.f);
        if (lane < 16 && x < XOUT) orow[x] = y;
    }
}

extern "C" void kernel_launch(void* const* d_in, const int* in_sizes, int n_in,
                              void* d_out, int out_size, void* d_ws, size_t ws_size,
                              hipStream_t stream) {
    const float* rho = (const float*)d_in[0];
    const float* w0  = (const float*)d_in[1];
    const float* b0  = (const float*)d_in[2];
    const float* Wh  = (const float*)d_in[3];
    const float* bh  = (const float*)d_in[4];
    const float* Wl  = (const float*)d_in[5];
    const float* bl  = (const float*)d_in[6];
    float* out = (float*)d_out;

    dim3 grid(NBLOCKS);   // 8192 blocks x 4 waves x 16 tiles x 16 pos = 8.39M
    dim3 block(256);
    cnn_mfma_kernel<<<grid, block, 0, stream>>>(rho, w0, b0, Wh, bh, Wl, bl, out);
}

// Round 11
// 137.395 us; speedup vs baseline: 72.0341x; 1.0374x over previous
//
#include <hip/hip_runtime.h>

typedef __attribute__((ext_vector_type(8))) _Float16 half8;
typedef __attribute__((ext_vector_type(2))) __fp16 fp16x2;
typedef __attribute__((ext_vector_type(4))) float f32x4;

#define XDIM 8192
#define XOUT 8191
#define TPW 16                     // tiles (of 16 positions) per wave
#define NTILES (1024 * 512)        // 512 tiles per row, 1024 rows
#define NBLOCKS (NTILES / TPW / 4) // 4 waves per block

// 8 halves: elems 0-3 -> k = 4g+j in k-block 0..15, elems 4-7 -> same in 16..31
union H8 {
    fp16x2 p[4];
    half8 v;
};

// Split 4 f32 into hi packs (pk01,pk23) and lo packs (pl01,pl23).
// cvt_pkrtz = 1 inst for 2 values; residual exact in f32.
#define SPLITP(H0, H1, H2, H3, PK01, PK23, PL01, PL23)                      \
    {                                                                       \
        PK01 = __builtin_amdgcn_cvt_pkrtz((H0), (H1));                      \
        PK23 = __builtin_amdgcn_cvt_pkrtz((H2), (H3));                      \
        const float _e0 = fmaf(-1.0f, (float)(PK01).x, (H0));               \
        const float _e1 = fmaf(-1.0f, (float)(PK01).y, (H1));               \
        const float _e2 = fmaf(-1.0f, (float)(PK23).x, (H2));               \
        const float _e3 = fmaf(-1.0f, (float)(PK23).y, (H3));               \
        PL01 = __builtin_amdgcn_cvt_pkrtz(_e0, _e1);                        \
        PL23 = __builtin_amdgcn_cvt_pkrtz(_e2, _e3);                        \
    }

#define MFMA32(A, B, C) __builtin_amdgcn_mfma_f32_16x16x32_f16((A), (B), (C), 0, 0, 0)

__global__ __launch_bounds__(256, 4) void cnn_mfma_kernel(
    const float* __restrict__ rho, const float* __restrict__ w0,
    const float* __restrict__ b0, const float* __restrict__ Wh,
    const float* __restrict__ bh, const float* __restrict__ Wl,
    const float* __restrict__ bl, float* __restrict__ out) {
    const int lane = threadIdx.x & 63;
    const int lm = lane & 15;          // A-row (out ch) / B-col (position) / D-col
    const int kb = (lane >> 4) * 4;    // k-base within block / D row-base

    // ---- per-layer A fragments: elems 0-3 = Whi[lm, kb+j], elems 4-7 = Wlo ----
    half8 A0, A1, A2, A3, A4;
#define LOADA(L, AF)                                                              \
    {                                                                             \
        float _w0 = (lm < 15 && kb + 0 < 15) ? Wh[(L)*225 + lm*15 + kb + 0] : 0.f;\
        float _w1 = (lm < 15 && kb + 1 < 15) ? Wh[(L)*225 + lm*15 + kb + 1] : 0.f;\
        float _w2 = (lm < 15 && kb + 2 < 15) ? Wh[(L)*225 + lm*15 + kb + 2] : 0.f;\
        float _w3 = (lm < 15 && kb + 3 < 15) ? Wh[(L)*225 + lm*15 + kb + 3] : 0.f;\
        H8 _u;                                                                    \
        fp16x2 _pk01, _pk23, _pl01, _pl23;                                        \
        SPLITP(_w0, _w1, _w2, _w3, _pk01, _pk23, _pl01, _pl23)                    \
        _u.p[0] = _pk01; _u.p[1] = _pk23;  /* k-block 0: hi */                    \
        _u.p[2] = _pl01; _u.p[3] = _pl23;  /* k-block 1: lo */                    \
        AF = _u.v;                                                                \
    }
    LOADA(0, A0)
    LOADA(1, A1)
    LOADA(2, A2)
    LOADA(3, A3)
    LOADA(4, A4)
#undef LOADA

    f32x4 bias0, bias1, bias2, bias3, bias4;   // C-init per layer (rows kb..kb+3)
#define LOADB(L, BV)                                                  \
    {                                                                 \
        (BV).x = (kb + 0 < 15) ? bh[(L)*15 + kb + 0] : 0.f;           \
        (BV).y = (kb + 1 < 15) ? bh[(L)*15 + kb + 1] : 0.f;           \
        (BV).z = (kb + 2 < 15) ? bh[(L)*15 + kb + 2] : 0.f;           \
        (BV).w = (kb + 3 < 15) ? bh[(L)*15 + kb + 3] : 0.f;           \
    }
    LOADB(0, bias0)
    LOADB(1, bias1)
    LOADB(2, bias2)
    LOADB(3, bias3)
    LOADB(4, bias4)
#undef LOADB

    // first-conv weights for this lane's 4 channels (kb..kb+3); ch 15 -> 0
    const float fw0_0 = (kb + 0 < 15) ? w0[2*(kb+0)]   : 0.f;
    const float fw1_0 = (kb + 0 < 15) ? w0[2*(kb+0)+1] : 0.f;
    const float fb_0  = (kb + 0 < 15) ? b0[kb+0]       : 0.f;
    const float fw0_1 = (kb + 1 < 15) ? w0[2*(kb+1)]   : 0.f;
    const float fw1_1 = (kb + 1 < 15) ? w0[2*(kb+1)+1] : 0.f;
    const float fb_1  = (kb + 1 < 15) ? b0[kb+1]       : 0.f;
    const float fw0_2 = (kb + 2 < 15) ? w0[2*(kb+2)]   : 0.f;
    const float fw1_2 = (kb + 2 < 15) ? w0[2*(kb+2)+1] : 0.f;
    const float fb_2  = (kb + 2 < 15) ? b0[kb+2]       : 0.f;
    const float fw0_3 = (kb + 3 < 15) ? w0[2*(kb+3)]   : 0.f;
    const float fw1_3 = (kb + 3 < 15) ? w0[2*(kb+3)+1] : 0.f;
    const float fb_3  = (kb + 3 < 15) ? b0[kb+3]       : 0.f;

    const float wl0 = (kb + 0 < 15) ? Wl[kb + 0] : 0.f;
    const float wl1 = (kb + 1 < 15) ? Wl[kb + 1] : 0.f;
    const float wl2 = (kb + 2 < 15) ? Wl[kb + 2] : 0.f;
    const float wl3 = (kb + 3 < 15) ? Wl[kb + 3] : 0.f;
    const float bl0 = bl[0];

    // ---- each wave owns 16 consecutive tiles of one row ----
    const int wid = blockIdx.x * 4 + (threadIdx.x >> 6);   // 0..32767
    const int brow = wid >> 5;                             // 32 waves per row
    const int xb = ((wid & 31) << 8) + lm;                 // + t*16, t in [0,16)
    const float* rrow = rho + (size_t)brow * XDIM;
    float* orow = out + (size_t)brow * XOUT;

#pragma unroll 2
    for (int t = 0; t < TPW; ++t) {
        const int x = xb + t * 16;                 // <= 8191
        const float r0 = rrow[x];
        const float r1 = rrow[(x < XDIM - 1) ? x + 1 : XDIM - 1];

        // first conv (k=2) + relu, this lane's 4 channels of its position
        float h0 = fmaxf(fmaf(fw0_0, r0, fmaf(fw1_0, r1, fb_0)), 0.f);
        float h1 = fmaxf(fmaf(fw0_1, r0, fmaf(fw1_1, r1, fb_1)), 0.f);
        float h2 = fmaxf(fmaf(fw0_2, r0, fmaf(fw1_2, r1, fb_2)), 0.f);
        float h3 = fmaxf(fmaf(fw0_3, r0, fmaf(fw1_3, r1, fb_3)), 0.f);

        // Per layer: D row (kb+reg) == B k (kb+j) -> lane's own 4 values feed
        // its B fragment directly. B1=[hhi|hhi], B2=[hlo|hlo]; with
        // A=[Whi|Wlo] two MFMAs give (Whi+Wlo)*(hhi+hlo) = full product.
#define HLAYER(AF, BV)                                       \
        {                                                    \
            fp16x2 pk01, pk23, pl01, pl23;                   \
            SPLITP(h0, h1, h2, h3, pk01, pk23, pl01, pl23)   \
            H8 _b1, _b2;                                     \
            _b1.p[0] = pk01; _b1.p[1] = pk23;                \
            _b1.p[2] = pk01; _b1.p[3] = pk23;                \
            _b2.p[0] = pl01; _b2.p[1] = pl23;                \
            _b2.p[2] = pl01; _b2.p[3] = pl23;                \
            f32x4 _acc = MFMA32((AF), _b1.v, (BV));          \
            _acc = MFMA32((AF), _b2.v, _acc);                \
            h0 = fmaxf(_acc.x, 0.f);                         \
            h1 = fmaxf(_acc.y, 0.f);                         \
            h2 = fmaxf(_acc.z, 0.f);                         \
            h3 = fmaxf(_acc.w, 0.f);                         \
        }
        HLAYER(A0, bias0)
        HLAYER(A1, bias1)
        HLAYER(A2, bias2)
        HLAYER(A3, bias3)
        HLAYER(A4, bias4)
#undef HLAYER

        // final dot: partial over this lane's 4 rows (f32), butterfly-sum the
        // 4 lane groups, clip; lanes 0-15 store.
        float s = fmaf(wl0, h0, fmaf(wl1, h1, fmaf(wl2, h2, wl3 * h3)));
        s += __shfl_xor(s, 16, 64);
        s += __shfl_xor(s, 32, 64);
        const float y = fminf(fmaxf(s + bl0, 0.f), 1.f);
        if (lane < 16 && x < XOUT) orow[x] = y;
    }
}

extern "C" void kernel_launch(void* const* d_in, const int* in_sizes, int n_in,
                              void* d_out, int out_size, void* d_ws, size_t ws_size,
                              hipStream_t stream) {
    const float* rho = (const float*)d_in[0];
    const float* w0  = (const float*)d_in[1];
    const float* b0  = (const float*)d_in[2];
    const float* Wh  = (const float*)d_in[3];
    const float* bh  = (const float*)d_in[4];
    const float* Wl  = (const float*)d_in[5];
    const float* bl  = (const float*)d_in[6];
    float* out = (float*)d_out;

    dim3 grid(NBLOCKS);   // 8192 blocks x 4 waves x 16 tiles x 16 pos = 8.39M
    dim3 block(256);
    cnn_mfma_kernel<<<grid, block, 0, stream>>>(rho, w0, b0, Wh, bh, Wl, bl, out);
}